// Round 1
// baseline (213.111 us; speedup 1.0000x reference)
//
#include <hip/hip_runtime.h>
#include <math.h>

typedef unsigned short u16;
typedef __attribute__((ext_vector_type(8))) short short8;   // 8 x bf16 (4 VGPRs)
typedef __attribute__((ext_vector_type(4))) float floatx4;  // 4 x f32

#define B_ROWS 4096
#define D_DIM  256
#define C_CLS  20000
#define C_PAD  20096      // 157 tiles * 128
#define NTILE  157
#define NSPLIT 16

__device__ __forceinline__ u16 f32_to_bf16(float f) {
  unsigned int b = __float_as_uint(f);
  b += 0x7fffu + ((b >> 16) & 1u);   // round-to-nearest-even
  return (u16)(b >> 16);
}

// ---------------- normalize embeddings: E -> En (f32) + Ebf (bf16) ----------
__global__ void normalize_embed(const float* __restrict__ emb,
                                float* __restrict__ En, u16* __restrict__ Ebf) {
  const int row = blockIdx.x, t = threadIdx.x;
  float x = emb[(size_t)row * D_DIM + t];
  float ss = x * x;
  for (int m = 1; m < 64; m <<= 1) ss += __shfl_xor(ss, m);
  __shared__ float red[4];
  if ((t & 63) == 0) red[t >> 6] = ss;
  __syncthreads();
  float tot = red[0] + red[1] + red[2] + red[3];
  float v = x * (1.0f / sqrtf(tot));
  En[(size_t)row * D_DIM + t] = v;
  Ebf[(size_t)row * D_DIM + t] = f32_to_bf16(v);
}

// ---------------- normalize weight rows -> Wn (bf16), pad rows = 0 ----------
__global__ void normalize_weight(const float* __restrict__ w, u16* __restrict__ Wn) {
  const int row = blockIdx.x, t = threadIdx.x;
  if (row >= C_CLS) { Wn[(size_t)row * D_DIM + t] = 0; return; }
  float x = w[(size_t)row * D_DIM + t];
  float ss = x * x;
  for (int m = 1; m < 64; m <<= 1) ss += __shfl_xor(ss, m);
  __shared__ float red[4];
  if ((t & 63) == 0) red[t >> 6] = ss;
  __syncthreads();
  float tot = red[0] + red[1] + red[2] + red[3];
  Wn[(size_t)row * D_DIM + t] = f32_to_bf16(x * (1.0f / sqrtf(tot)));
}

__global__ void zero_f(float* __restrict__ p, int n) {
  int i = blockIdx.x * 256 + threadIdx.x;
  if (i < n) p[i] = 0.0f;
}

// ---------------- fused cosine GEMM + AM-softmax partial sums ---------------
// grid (32 row-tiles, 16 splits), block 256 (4 waves in 2x2 of 64x64)
__global__ __launch_bounds__(256, 2) void gemm_softmax(
    const u16* __restrict__ Ebf, const u16* __restrict__ Wn,
    const int* __restrict__ labels, float* __restrict__ partial_s,
    float* __restrict__ label_cos) {
  __shared__ u16 Bs[128 * 256];   // 64 KB, XOR-swizzled chunks of 8 bf16
  const int tid = threadIdx.x;
  const int w = tid >> 6, lane = tid & 63, quad = lane >> 4, c16 = lane & 15;
  const int rt = blockIdx.x, sp = blockIdx.y;
  const int wr = (w & 1) * 64;   // wave row offset
  const int wc = (w >> 1) * 64;  // wave col offset

  // ---- stage A tile (rows rt*128..+127, full K) with XOR swizzle ----
  {
    const u16* Abase = Ebf + (size_t)rt * 128 * D_DIM;
#pragma unroll 4
    for (int it = 0; it < 16; ++it) {
      int L = it * 256 + tid;
      int n = L >> 5, cs = L & 31;
      int c = cs ^ (n & 31);
      uint4 v = *(const uint4*)(Abase + n * D_DIM + c * 8);
      *(uint4*)((char*)Bs + L * 16) = v;
    }
  }
  __syncthreads();
  // ---- A fragments to registers: a[mt][kt], rows wr+mt*16+c16 ----
  short8 a[4][8];
#pragma unroll
  for (int mt = 0; mt < 4; ++mt) {
    int rl = wr + mt * 16 + c16;
    int rx = rl & 31;
#pragma unroll
    for (int kt = 0; kt < 8; ++kt) {
      int chunk = (kt * 4 + quad) ^ rx;
      a[mt][kt] = *(const short8*)((const char*)Bs + rl * 512 + chunk * 16);
    }
  }
  int lab[4][4];
  float run_s[4][4];
#pragma unroll
  for (int mt = 0; mt < 4; ++mt)
#pragma unroll
    for (int rg = 0; rg < 4; ++rg) {
      int gr = rt * 128 + wr + mt * 16 + quad * 4 + rg;
      lab[mt][rg] = labels[gr];
      run_s[mt][rg] = 0.0f;
    }
  __syncthreads();  // A reads done before Bs is overwritten

  // ---- loop over class tiles assigned to this split ----
  for (int t = sp; t < NTILE; t += NSPLIT) {
    const int cb = t * 128;
    {
      const u16* Bbase = Wn + (size_t)cb * D_DIM;
#pragma unroll 4
      for (int it = 0; it < 16; ++it) {
        int L = it * 256 + tid;
        int n = L >> 5, cs = L & 31;
        int c = cs ^ (n & 31);
        uint4 v = *(const uint4*)(Bbase + n * D_DIM + c * 8);
        *(uint4*)((char*)Bs + L * 16) = v;
      }
    }
    __syncthreads();
#pragma unroll
    for (int nt = 0; nt < 4; ++nt) {
      int nl = wc + nt * 16 + c16;
      int nx = nl & 31;
      floatx4 acc[4] = {};
#pragma unroll
      for (int kt = 0; kt < 8; ++kt) {
        short8 b = *(const short8*)((const char*)Bs + nl * 512 +
                                    (((kt * 4 + quad) ^ nx) * 16));
#pragma unroll
        for (int mt = 0; mt < 4; ++mt)
          acc[mt] = __builtin_amdgcn_mfma_f32_16x16x32_bf16(a[mt][kt], b, acc[mt], 0, 0, 0);
      }
      // epilogue: margin + exp(logit - 30), accumulate per-lane
      int cls = cb + wc + nt * 16 + c16;
      bool valid = (cls < C_CLS);
#pragma unroll
      for (int mt = 0; mt < 4; ++mt)
#pragma unroll
        for (int rg = 0; rg < 4; ++rg) {
          float v = acc[mt][rg];
          bool isLab = (cls == lab[mt][rg]);
          float logit = 30.0f * v - (isLab ? 9.0f : 0.0f);
          float e = valid ? __expf(logit - 30.0f) : 0.0f;
          run_s[mt][rg] += e;
          if (isLab) {
            int gr = rt * 128 + wr + mt * 16 + quad * 4 + rg;
            label_cos[gr] = v;
          }
        }
    }
    __syncthreads();
  }
  // ---- reduce partial sums across the 16 column lanes, write ----
#pragma unroll
  for (int mt = 0; mt < 4; ++mt)
#pragma unroll
    for (int rg = 0; rg < 4; ++rg) {
      float s = run_s[mt][rg];
      s += __shfl_xor(s, 1);
      s += __shfl_xor(s, 2);
      s += __shfl_xor(s, 4);
      s += __shfl_xor(s, 8);
      if (c16 == 0) {
        int rl = wr + mt * 16 + quad * 4 + rg;
        int half = w >> 1;  // waves 0/2 share rows, cover different cols
        partial_s[(((size_t)rt * NSPLIT + sp) * 2 + half) * 128 + rl] = s;
      }
    }
}

// ---------------- intra-class pair distances -> per-class dsum/cnt ----------
__global__ void pair_intra(const float* __restrict__ En, const int* __restrict__ labels,
                           float* __restrict__ dsum, float* __restrict__ cnt) {
  const int i = blockIdx.x, t = threadIdx.x;
  __shared__ float ei[D_DIM];
  __shared__ int li_s;
  ei[t] = En[(size_t)i * D_DIM + t];
  if (t == 0) li_s = labels[i];
  __syncthreads();
  const int li = li_s;
  for (int j = i + 1 + t; j < B_ROWS; j += 256) {
    if (labels[j] == li) {
      const float4* ej4 = (const float4*)(En + (size_t)j * D_DIM);
      float d = 0.0f;
#pragma unroll 8
      for (int k = 0; k < 64; ++k) {
        float4 e4 = ej4[k];
        d += ei[4 * k] * e4.x + ei[4 * k + 1] * e4.y +
             ei[4 * k + 2] * e4.z + ei[4 * k + 3] * e4.w;
      }
      atomicAdd(&dsum[li], 1.0f - d);
      atomicAdd(&cnt[li], 1.0f);
    }
  }
}

// ---------------- final reduction: am_loss + intra_loss + total -------------
__global__ void finalize(const float* __restrict__ partial_s,
                         const float* __restrict__ label_cos,
                         const float* __restrict__ dsum, const float* __restrict__ cnt,
                         float* __restrict__ out) {
  __shared__ float red[512];
  __shared__ float keep[2];
  const int t = threadIdx.x;
  float nlp = 0.0f;
  for (int r = t; r < B_ROWS; r += 512) {
    int rtile = r >> 7, rl = r & 127;
    const float* ps = partial_s + (size_t)rtile * NSPLIT * 2 * 128;
    float S = 0.0f;
    for (int s = 0; s < NSPLIT * 2; ++s) S += ps[s * 128 + rl];
    float logit_y = 30.0f * label_cos[r] - 9.0f;
    nlp += (30.0f + logf(S)) - logit_y;
  }
  red[t] = nlp;
  __syncthreads();
  for (int s = 256; s > 0; s >>= 1) {
    if (t < s) red[t] += red[t + s];
    __syncthreads();
  }
  if (t == 0) keep[0] = red[0];
  __syncthreads();

  float pg = 0.0f, nv = 0.0f;
  for (int c = t; c < C_CLS; c += 512) {
    float ct = cnt[c];
    if (ct > 0.0f) {
      float m = dsum[c] / ct;
      pg += fmaxf(m - 0.5f, 0.0f);
      nv += 1.0f;
    }
  }
  red[t] = pg;
  __syncthreads();
  for (int s = 256; s > 0; s >>= 1) {
    if (t < s) red[t] += red[t + s];
    __syncthreads();
  }
  if (t == 0) keep[1] = red[0];
  __syncthreads();
  red[t] = nv;
  __syncthreads();
  for (int s = 256; s > 0; s >>= 1) {
    if (t < s) red[t] += red[t + s];
    __syncthreads();
  }
  if (t == 0) {
    float am = keep[0] / (float)B_ROWS;
    float nvalid = red[0];
    float intra = (nvalid > 0.0f) ? (keep[1] / nvalid) : 0.0f;
    out[0] = am + 0.1f * intra;
    out[1] = am;
    out[2] = intra;
  }
}

extern "C" void kernel_launch(void* const* d_in, const int* in_sizes, int n_in,
                              void* d_out, int out_size, void* d_ws, size_t ws_size,
                              hipStream_t stream) {
  const float* emb = (const float*)d_in[0];
  const int* labels = (const int*)d_in[1];
  const float* weight = (const float*)d_in[2];
  float* out = (float*)d_out;
  char* ws = (char*)d_ws;

  float* En        = (float*)(ws);                 // 4096*256*4   = 4,194,304
  u16*   Ebf       = (u16*)(ws + 4194304);         // 4096*256*2   = 2,097,152
  u16*   Wn        = (u16*)(ws + 6291456);         // 20096*256*2  = 10,289,152
  float* partial_s = (float*)(ws + 16580608);      // 32*16*2*128*4 = 524,288
  float* label_cos = (float*)(ws + 17104896);      // 4096*4       = 16,384
  float* dsum      = (float*)(ws + 17121280);      // 20000*4      = 80,000
  float* cnt       = (float*)(ws + 17201280);      // 20000*4      = 80,000

  normalize_embed<<<B_ROWS, 256, 0, stream>>>(emb, En, Ebf);
  normalize_weight<<<C_PAD, 256, 0, stream>>>(weight, Wn);
  zero_f<<<(40000 + 255) / 256, 256, 0, stream>>>(dsum, 40000);  // dsum+cnt contiguous
  gemm_softmax<<<dim3(32, NSPLIT), 256, 0, stream>>>(Ebf, Wn, labels, partial_s, label_cos);
  pair_intra<<<B_ROWS, 256, 0, stream>>>(En, labels, dsum, cnt);
  finalize<<<1, 512, 0, stream>>>(partial_s, label_cos, dsum, cnt, out);
}

// Round 2
// 175.054 us; speedup vs baseline: 1.2174x; 1.2174x over previous
//
#include <hip/hip_runtime.h>
#include <math.h>

typedef unsigned short u16;
typedef __attribute__((ext_vector_type(8))) short short8;   // 8 x bf16 (4 VGPRs)
typedef __attribute__((ext_vector_type(4))) float floatx4;  // 4 x f32

#define B_ROWS 4096
#define D_DIM  256
#define C_CLS  20000
#define C_PAD  20096      // 157 tiles * 128
#define NTILE  157
#define NSPLIT 16

#define SC  43.280851227f   // 30 * log2(e)
#define M9  12.984255369f   // 9 * log2(e)

__device__ __forceinline__ u16 f32_to_bf16(float f) {
  unsigned int b = __float_as_uint(f);
  b += 0x7fffu + ((b >> 16) & 1u);   // round-to-nearest-even
  return (u16)(b >> 16);
}

// ---- normalize embeddings: wave-per-row, 4 rows per block ----
__global__ void normalize_embed(const float* __restrict__ emb,
                                float* __restrict__ En, u16* __restrict__ Ebf) {
  const int r = blockIdx.x * 4 + (threadIdx.x >> 6);
  const int lane = threadIdx.x & 63;
  float4 v = ((const float4*)(emb + (size_t)r * D_DIM))[lane];
  float ss = v.x * v.x + v.y * v.y + v.z * v.z + v.w * v.w;
  for (int m = 1; m < 64; m <<= 1) ss += __shfl_xor(ss, m);
  float k = 1.0f / sqrtf(ss);
  v.x *= k; v.y *= k; v.z *= k; v.w *= k;
  ((float4*)(En + (size_t)r * D_DIM))[lane] = v;
  ushort4 b;
  b.x = f32_to_bf16(v.x); b.y = f32_to_bf16(v.y);
  b.z = f32_to_bf16(v.z); b.w = f32_to_bf16(v.w);
  ((ushort4*)(Ebf + (size_t)r * D_DIM))[lane] = b;
}

// ---- normalize weight rows (bf16 out), pad rows zeroed ----
__global__ void normalize_weight(const float* __restrict__ w, u16* __restrict__ Wn) {
  const int r = blockIdx.x * 4 + (threadIdx.x >> 6);
  const int lane = threadIdx.x & 63;
  if (r >= C_CLS) {
    ushort4 z = {0, 0, 0, 0};
    ((ushort4*)(Wn + (size_t)r * D_DIM))[lane] = z;
    return;
  }
  float4 v = ((const float4*)(w + (size_t)r * D_DIM))[lane];
  float ss = v.x * v.x + v.y * v.y + v.z * v.z + v.w * v.w;
  for (int m = 1; m < 64; m <<= 1) ss += __shfl_xor(ss, m);
  float k = 1.0f / sqrtf(ss);
  ushort4 b;
  b.x = f32_to_bf16(v.x * k); b.y = f32_to_bf16(v.y * k);
  b.z = f32_to_bf16(v.z * k); b.w = f32_to_bf16(v.w * k);
  ((ushort4*)(Wn + (size_t)r * D_DIM))[lane] = b;
}

// ---- fused cosine GEMM + exp-sum (no margin in-loop; fixed max=30) ----
// grid (32 row-tiles, 16 splits), block 256 = 4 waves in 2x2, wave tile 64x64
__global__ __launch_bounds__(256, 2) void gemm_softmax(
    const u16* __restrict__ Ebf, const u16* __restrict__ Wn,
    float* __restrict__ row_S) {
  __shared__ uint4 Bs[4096];   // 64 KB; row n chunk c (16B) at slot c^(n&7)
  char* lds = (char*)Bs;
  const int tid = threadIdx.x;
  const int w = tid >> 6, lane = tid & 63, quad = lane >> 4, c16 = lane & 15;
  const int rt = blockIdx.x, sp = blockIdx.y;
  const int wr = (w & 1) * 64;   // wave row offset
  const int wc = (w >> 1) * 64;  // wave col offset

  // staging source byte-offsets within a 128x512B tile (constant per thread)
  int preSrc[16];
#pragma unroll
  for (int i = 0; i < 16; ++i) {
    int off = i * 4096 + tid * 16;
    int n = off >> 9;
    int slot = (off >> 4) & 31;
    int c = slot ^ (n & 7);
    preSrc[i] = n * 512 + c * 16;
  }
  auto stage = [&](const char* srcBase) {
#pragma unroll
    for (int i = 0; i < 16; ++i) {
      __builtin_amdgcn_global_load_lds(
          (const __attribute__((address_space(1))) unsigned int*)(srcBase + preSrc[i]),
          (__attribute__((address_space(3))) unsigned int*)(lds + i * 4096 + tid * 16),
          16, 0, 0);
    }
  };

  // ---- stage A tile, load register-resident A fragments ----
  stage((const char*)(Ebf + (size_t)rt * 128 * D_DIM));
  __syncthreads();
  short8 a[4][8];
#pragma unroll
  for (int mt = 0; mt < 4; ++mt) {
    int rl = wr + mt * 16 + c16;
    int b = (rl >> 2) & 1;
    int bP = rl * 512 + (quad ^ (rl & 3)) * 16 + b * 64;
    int bM = bP - 128 * b;
#pragma unroll
    for (int kt = 0; kt < 8; ++kt) {
      int base = (kt & 1) ? bM : bP;
      int offk = (kt >> 1) * 128 + (kt & 1) * 64;
      a[mt][kt] = *(const short8*)(lds + base + offk);
    }
  }
  __syncthreads();  // A reads done before Bs is overwritten

  // per-lane B read bases (constant across tiles)
  int bPn[4], bMn[4];
#pragma unroll
  for (int nt = 0; nt < 4; ++nt) {
    int nl = wc + nt * 16 + c16;
    int b = (nl >> 2) & 1;
    bPn[nt] = nl * 512 + (quad ^ (nl & 3)) * 16 + b * 64;
    bMn[nt] = bPn[nt] - 128 * b;
  }

  float run_s[4][4] = {};
  for (int t = sp; t < NTILE; t += NSPLIT) {
    stage((const char*)(Wn + (size_t)(t * 128) * D_DIM));
    __syncthreads();
#pragma unroll
    for (int nt = 0; nt < 4; ++nt) {
      floatx4 acc[4] = {};
#pragma unroll
      for (int kt = 0; kt < 8; ++kt) {
        int base = (kt & 1) ? bMn[nt] : bPn[nt];
        int offk = (kt >> 1) * 128 + (kt & 1) * 64;
        short8 b = *(const short8*)(lds + base + offk);
#pragma unroll
        for (int mt = 0; mt < 4; ++mt)
          acc[mt] = __builtin_amdgcn_mfma_f32_16x16x32_bf16(a[mt][kt], b, acc[mt], 0, 0, 0);
      }
#pragma unroll
      for (int mt = 0; mt < 4; ++mt)
#pragma unroll
        for (int rg = 0; rg < 4; ++rg)
          run_s[mt][rg] += __builtin_amdgcn_exp2f(fmaf(SC, acc[mt][rg], -SC));
    }
    __syncthreads();
  }
  // ---- reduce across the 16 column lanes, one atomic per row per wave ----
#pragma unroll
  for (int mt = 0; mt < 4; ++mt)
#pragma unroll
    for (int rg = 0; rg < 4; ++rg) {
      float s = run_s[mt][rg];
      s += __shfl_xor(s, 1);
      s += __shfl_xor(s, 2);
      s += __shfl_xor(s, 4);
      s += __shfl_xor(s, 8);
      if (c16 == 0)
        atomicAdd(&row_S[rt * 128 + wr + mt * 16 + quad * 4 + rg], s);
    }
}

// ---- per-row label cosine, f32 (wave per row, 4 rows/block) ----
__global__ void label_cos_k(const float* __restrict__ En, const float* __restrict__ W,
                            const int* __restrict__ labels, float* __restrict__ lcos) {
  const int r = blockIdx.x * 4 + (threadIdx.x >> 6);
  const int lane = threadIdx.x & 63;
  const int lab = labels[r];
  float4 e = ((const float4*)(En + (size_t)r * D_DIM))[lane];
  float4 v = ((const float4*)(W + (size_t)lab * D_DIM))[lane];
  float dot = e.x * v.x + e.y * v.y + e.z * v.z + e.w * v.w;
  float ss = v.x * v.x + v.y * v.y + v.z * v.z + v.w * v.w;
  for (int m = 1; m < 64; m <<= 1) {
    dot += __shfl_xor(dot, m);
    ss += __shfl_xor(ss, m);
  }
  if (lane == 0) lcos[r] = dot / sqrtf(ss);
}

// ---- intra-class pair distances -> per-class dsum/cnt ----
__global__ void pair_intra(const float* __restrict__ En, const int* __restrict__ labels,
                           float* __restrict__ dsum, float* __restrict__ cnt) {
  const int i = blockIdx.x, t = threadIdx.x;
  __shared__ float ei[D_DIM];
  __shared__ int li_s;
  ei[t] = En[(size_t)i * D_DIM + t];
  if (t == 0) li_s = labels[i];
  __syncthreads();
  const int li = li_s;
  for (int j = i + 1 + t; j < B_ROWS; j += 256) {
    if (labels[j] == li) {
      const float4* ej4 = (const float4*)(En + (size_t)j * D_DIM);
      float d = 0.0f;
#pragma unroll 8
      for (int k = 0; k < 64; ++k) {
        float4 e4 = ej4[k];
        d += ei[4 * k] * e4.x + ei[4 * k + 1] * e4.y +
             ei[4 * k + 2] * e4.z + ei[4 * k + 3] * e4.w;
      }
      atomicAdd(&dsum[li], 1.0f - d);
      atomicAdd(&cnt[li], 1.0f);
    }
  }
}

// ---- finalize: margin + pad corrections, both losses ----
__global__ void finalize(const float* __restrict__ row_S, const float* __restrict__ lcos,
                         const float* __restrict__ dsum, const float* __restrict__ cnt,
                         float* __restrict__ out) {
  __shared__ float red[1024];
  __shared__ float keep[2];
  const int t = threadIdx.x;
  const float padc = 96.0f * __builtin_amdgcn_exp2f(-SC);  // pad classes: v == 0 exactly
  float nlp = 0.0f;
  for (int r = t; r < B_ROWS; r += 1024) {
    float c = lcos[r];
    float S = row_S[r] - padc
            + __builtin_amdgcn_exp2f(fmaf(SC, c, -SC - M9))   // label term with margin
            - __builtin_amdgcn_exp2f(fmaf(SC, c, -SC));       // remove unmargined label term
    nlp += 30.0f + logf(S) - fmaf(30.0f, c, -9.0f);
  }
  red[t] = nlp;
  __syncthreads();
  for (int s = 512; s > 0; s >>= 1) { if (t < s) red[t] += red[t + s]; __syncthreads(); }
  if (t == 0) keep[0] = red[0];
  __syncthreads();

  float pg = 0.0f, nv = 0.0f;
  for (int c = t; c < C_CLS; c += 1024) {
    float ct = cnt[c];
    if (ct > 0.0f) {
      pg += fmaxf(dsum[c] / ct - 0.5f, 0.0f);
      nv += 1.0f;
    }
  }
  red[t] = pg;
  __syncthreads();
  for (int s = 512; s > 0; s >>= 1) { if (t < s) red[t] += red[t + s]; __syncthreads(); }
  if (t == 0) keep[1] = red[0];
  __syncthreads();
  red[t] = nv;
  __syncthreads();
  for (int s = 512; s > 0; s >>= 1) { if (t < s) red[t] += red[t + s]; __syncthreads(); }
  if (t == 0) {
    float am = keep[0] * (1.0f / (float)B_ROWS);
    float nvalid = red[0];
    float intra = (nvalid > 0.0f) ? (keep[1] / nvalid) : 0.0f;
    out[0] = am + 0.1f * intra;
    out[1] = am;
    out[2] = intra;
  }
}

extern "C" void kernel_launch(void* const* d_in, const int* in_sizes, int n_in,
                              void* d_out, int out_size, void* d_ws, size_t ws_size,
                              hipStream_t stream) {
  const float* emb = (const float*)d_in[0];
  const int* labels = (const int*)d_in[1];
  const float* weight = (const float*)d_in[2];
  float* out = (float*)d_out;
  char* ws = (char*)d_ws;

  float* En    = (float*)(ws);                 // 4096*256*4   = 4,194,304
  u16*   Ebf   = (u16*)(ws + 4194304);         // 4096*256*2   = 2,097,152
  u16*   Wn    = (u16*)(ws + 6291456);         // 20096*256*2  = 10,289,152 -> 16,580,608
  float* row_S = (float*)(ws + 16580608);      // 4096*4  = 16,384 -> 16,596,992
  float* dsum  = (float*)(ws + 16596992);      // 20000*4 = 80,000 -> 16,676,992
  float* cnt   = (float*)(ws + 16676992);      // 20000*4 = 80,000 -> 16,756,992
  float* lcos  = (float*)(ws + 16756992);      // 4096*4  = 16,384 -> 16,773,376

  hipMemsetAsync(ws + 16580608, 0, 176384, stream);  // row_S + dsum + cnt
  normalize_embed<<<B_ROWS / 4, 256, 0, stream>>>(emb, En, Ebf);
  normalize_weight<<<C_PAD / 4, 256, 0, stream>>>(weight, Wn);
  gemm_softmax<<<dim3(32, NSPLIT), 256, 0, stream>>>(Ebf, Wn, row_S);
  label_cos_k<<<B_ROWS / 4, 256, 0, stream>>>(En, weight, labels, lcos);
  pair_intra<<<B_ROWS, 256, 0, stream>>>(En, labels, dsum, cnt);
  finalize<<<1, 1024, 0, stream>>>(row_S, lcos, dsum, cnt, out);
}